// Round 10
// baseline (128471.484 us; speedup 1.0000x reference)
//
#include <hip/hip_runtime.h>
#include <hip/hip_bf16.h>
#include <cstdint>

// LSTM, T=32768 steps, C=512, I=1024 (x 512 | h 512), fp32.
//   1) gx = Wx@x_t + b  -- GEMM over all timesteps (chunked in ws)
//   2) serial recurrence: 64 blocks x 320 threads (5 waves).
//      WAVE 0 = comms wave: polls NEXT step's tagged h words (per-word pending
//      mask, independent retirement) into LDS while waves 1-4 compute the
//      current step -> detection RTT hides under compute (R8 paid it serially:
//      2.09us/step = 1.6 detect + 0.5 compute).
//      Waves 1-4 = compute: R8's proven zero-conflict LDS weight layout.
//      Sync: tagged-word MALL mailbox (u64 atomicExch, tag<<32|h) -- the
//      protocol class proven in R4-R8. No XCD assumptions (R9's failure).

#define T_TOTAL 32768
#define NBLK 64

__device__ __forceinline__ float sigm(float x) {
    return 1.0f / (1.0f + __expf(-x));
}
__device__ __forceinline__ float tanh_fast(float x) {
    float ax = fabsf(x);
    float e = __expf(2.0f * ax);          // +inf for large ax is fine -> t = 1
    float t = 1.0f - 2.0f / (e + 1.0f);
    return copysignf(t, x);
}

// ---------------------------------------------------------------------------
// GEMM: for fused c-row jg, gate g: block b = jg>>3, r = jg&7:
//   gx word = (jg>>3)*32 + (jg&7)*4 + g   (block-major, float4 per (b,r))
// ---------------------------------------------------------------------------
__global__ __launch_bounds__(256, 1) void lstm_gemm_x(
    const float* __restrict__ x,
    const float* __restrict__ wf, const float* __restrict__ wi,
    const float* __restrict__ wc, const float* __restrict__ wo,
    const float* __restrict__ bf, const float* __restrict__ bi,
    const float* __restrict__ bc, const float* __restrict__ bo,
    float* __restrict__ gx, int t0, int tend)
{
    __shared__ float xs[16][512];
    const int tid = threadIdx.x;
    const int tt0 = t0 + blockIdx.x * 16;
    const int j0  = blockIdx.y * 128;

    #pragma unroll
    for (int i = 0; i < 8; ++i) {
        int idx  = tid + i * 256;
        int trow = idx >> 7, kq = idx & 127;
        int t    = tt0 + trow;
        float4 v = make_float4(0.f, 0.f, 0.f, 0.f);
        if (t < tend) v = *(const float4*)(x + (size_t)t * 512 + kq * 4);
        *(float4*)&xs[trow][kq * 4] = v;
    }
    __syncthreads();

    const int j  = j0 + (tid & 127);
    const int th = tid >> 7;
    const int g  = j >> 9;
    const int jg = j & 511;
    const float* Wg = (g == 0) ? wf : (g == 1) ? wi : (g == 2) ? wc : wo;
    const float* Bg = (g == 0) ? bf : (g == 1) ? bi : (g == 2) ? bc : bo;
    const float* wrow = Wg + (size_t)jg * 1024;

    float acc[8];
    #pragma unroll
    for (int i = 0; i < 8; ++i) acc[i] = 0.f;

    for (int k = 0; k < 512; k += 4) {
        float4 w4 = *(const float4*)(wrow + k);
        #pragma unroll
        for (int tt = 0; tt < 8; ++tt) {
            float4 x4 = *(const float4*)&xs[th * 8 + tt][k];
            acc[tt] = fmaf(w4.x, x4.x, acc[tt]);
            acc[tt] = fmaf(w4.y, x4.y, acc[tt]);
            acc[tt] = fmaf(w4.z, x4.z, acc[tt]);
            acc[tt] = fmaf(w4.w, x4.w, acc[tt]);
        }
    }

    const float bias = Bg[jg];
    const int   obase = (jg >> 3) * 32 + (jg & 7) * 4 + g;
    #pragma unroll
    for (int tt = 0; tt < 8; ++tt) {
        int t = tt0 + th * 8 + tt;
        if (t < tend) gx[(size_t)(t - t0) * 2048 + obase] = acc[tt] + bias;
    }
}

// ---------------------------------------------------------------------------
// Serial recurrence. 64 blocks x 320 threads (5 waves; all co-resident).
// Wave 0 (lanes 0..63): comms. Lane l owns words {l + 64i}, i=0..7, of the
//   target slot; pending-mask loop retires words as their tag matches.
// Waves 1-4 (ct = tid-64 in [0,256)): compute, R8 mapping:
//   r = ct>>5 (row 0..7), seg = ct&31, w = ct>>6 (0..3), l = ct&63.
//   Weight LDS wlds4[w*1024 + g*256 + jj*64 + l] (lane-linear, 0 conflicts).
// Per step t: [wave0: poll tags t+1 into hl[t&1] unless last iter] ||
//   [waves 1-4: gx4, 16 w-b128 reads, 4 h-b128 reads, 64 FMA, 5x shfl_xor,
//    seg==0: activations, c/h update, atomicExch publish (tag t+1)];
//   one barrier. Prologue polls tags t0 into hl[(t0&1)^1] (zero-init passes
//   t0=0). Slot-reuse induction identical to R6-R8.
// ---------------------------------------------------------------------------
__global__ __launch_bounds__(320, 1) void lstm_serial(
    const float* __restrict__ wf, const float* __restrict__ wi,
    const float* __restrict__ wc, const float* __restrict__ wo,
    const float* __restrict__ gx,
    unsigned long long* __restrict__ hdq,   // [2][512] tagged h words
    float* __restrict__ cstate,
    int t0, int steps, float* __restrict__ out)
{
    __shared__ alignas(16) float4 wlds4[4096];  // 64 KB, reader-keyed layout
    __shared__ alignas(16) float  hl[2][512];   // parity-double-buffered h

    const int b    = blockIdx.x;           // 0..63
    const int tid  = threadIdx.x;          // 0..319
    const int wave = tid >> 6;             // 0..4
    const int lane = tid & 63;

    float cold = 0.f;
    if (wave >= 1) {                       // compute waves stage weights
        const int ct = tid - 64;           // 0..255
        #pragma unroll
        for (int k = 0; k < 16; ++k) {
            int idx = k * 256 + ct;        // 0..4095
            int ll  = idx & 63;
            int jj  = (idx >> 6) & 3;
            int gg  = (idx >> 8) & 3;
            int ww  = idx >> 10;
            const float* Wp = (gg == 0) ? wf : (gg == 1) ? wi
                             : (gg == 2) ? wc : wo;
            int row = b * 8 + ww * 2 + (ll >> 5);
            wlds4[idx] = *(const float4*)(Wp + (size_t)row * 1024 + 512
                                          + 4 * (ll & 31) + 128 * jj);
        }
        cold = cstate[b * 8 + (ct >> 5)];
    }

    // prologue: wave 0 stages h_{t0-1} (tags == t0) into hl[sp0]
    if (wave == 0) {
        const int sp0 = (t0 & 1) ^ 1;
        const unsigned need = (unsigned)t0;
        const unsigned long long* src = hdq + (size_t)sp0 * 512 + lane;
        unsigned pend = 0xFFu;
        int guard = 0;
        while (pend && ++guard < (1 << 20)) {
            #pragma unroll
            for (int i = 0; i < 8; ++i) {
                if (pend & (1u << i)) {
                    unsigned long long v = __hip_atomic_load(src + i * 64,
                        __ATOMIC_RELAXED, __HIP_MEMORY_SCOPE_AGENT);
                    if ((unsigned)(v >> 32) == need) {
                        hl[sp0][lane + i * 64] = __uint_as_float((unsigned)v);
                        pend &= ~(1u << i);
                    }
                }
            }
        }
    }
    __syncthreads();

    const float4* hl4 = (const float4*)hl;

    for (int s = 0; s < steps; ++s) {
        const int t  = t0 + s;
        const int sp = (t & 1) ^ 1;        // slot holding h_{t-1} (staged in LDS)
        const int sc = t & 1;              // slot receiving h_t

        if (wave == 0) {
            // poll h_t (tags t+1) into hl[sc] while compute waves work on t
            if (s < steps - 1) {
                const unsigned need = (unsigned)(t + 1);
                const unsigned long long* src = hdq + (size_t)sc * 512 + lane;
                unsigned pend = 0xFFu;
                int guard = 0;
                while (pend && ++guard < (1 << 20)) {
                    #pragma unroll
                    for (int i = 0; i < 8; ++i) {
                        if (pend & (1u << i)) {
                            unsigned long long v = __hip_atomic_load(src + i * 64,
                                __ATOMIC_RELAXED, __HIP_MEMORY_SCOPE_AGENT);
                            if ((unsigned)(v >> 32) == need) {
                                hl[sc][lane + i * 64] =
                                    __uint_as_float((unsigned)v);
                                pend &= ~(1u << i);
                            }
                        }
                    }
                }
            }
        } else {
            const int ct  = tid - 64;
            const int r   = ct >> 5;
            const int seg = ct & 31;
            const int w   = ct >> 6;
            const int l   = ct & 63;
            const int wb  = w * 1024 + l;

            float4 gx4 = make_float4(0.f, 0.f, 0.f, 0.f);
            if (seg == 0)
                gx4 = *(const float4*)(gx + (size_t)s * 2048 + b * 32 + r * 4);

            // weights: 16 lane-linear b128 reads (0 conflicts, R8-proven)
            float4 w00 = wlds4[wb +   0], w01 = wlds4[wb +  64];
            float4 w02 = wlds4[wb + 128], w03 = wlds4[wb + 192];
            float4 w10 = wlds4[wb + 256], w11 = wlds4[wb + 320];
            float4 w12 = wlds4[wb + 384], w13 = wlds4[wb + 448];
            float4 w20 = wlds4[wb + 512], w21 = wlds4[wb + 576];
            float4 w22 = wlds4[wb + 640], w23 = wlds4[wb + 704];
            float4 w30 = wlds4[wb + 768], w31 = wlds4[wb + 832];
            float4 w32 = wlds4[wb + 896], w33 = wlds4[wb + 960];

            // h: 4 lane-linear b128 reads (r-pairs broadcast)
            float4 h0 = hl4[sp * 128 + seg];
            float4 h1 = hl4[sp * 128 + seg + 32];
            float4 h2 = hl4[sp * 128 + seg + 64];
            float4 h3 = hl4[sp * 128 + seg + 96];

            float a0 = 0.f, a1 = 0.f, a2 = 0.f, a3 = 0.f;
            a0 = fmaf(w00.x, h0.x, a0); a0 = fmaf(w00.y, h0.y, a0);
            a0 = fmaf(w00.z, h0.z, a0); a0 = fmaf(w00.w, h0.w, a0);
            a0 = fmaf(w01.x, h1.x, a0); a0 = fmaf(w01.y, h1.y, a0);
            a0 = fmaf(w01.z, h1.z, a0); a0 = fmaf(w01.w, h1.w, a0);
            a0 = fmaf(w02.x, h2.x, a0); a0 = fmaf(w02.y, h2.y, a0);
            a0 = fmaf(w02.z, h2.z, a0); a0 = fmaf(w02.w, h2.w, a0);
            a0 = fmaf(w03.x, h3.x, a0); a0 = fmaf(w03.y, h3.y, a0);
            a0 = fmaf(w03.z, h3.z, a0); a0 = fmaf(w03.w, h3.w, a0);

            a1 = fmaf(w10.x, h0.x, a1); a1 = fmaf(w10.y, h0.y, a1);
            a1 = fmaf(w10.z, h0.z, a1); a1 = fmaf(w10.w, h0.w, a1);
            a1 = fmaf(w11.x, h1.x, a1); a1 = fmaf(w11.y, h1.y, a1);
            a1 = fmaf(w11.z, h1.z, a1); a1 = fmaf(w11.w, h1.w, a1);
            a1 = fmaf(w12.x, h2.x, a1); a1 = fmaf(w12.y, h2.y, a1);
            a1 = fmaf(w12.z, h2.z, a1); a1 = fmaf(w12.w, h2.w, a1);
            a1 = fmaf(w13.x, h3.x, a1); a1 = fmaf(w13.y, h3.y, a1);
            a1 = fmaf(w13.z, h3.z, a1); a1 = fmaf(w13.w, h3.w, a1);

            a2 = fmaf(w20.x, h0.x, a2); a2 = fmaf(w20.y, h0.y, a2);
            a2 = fmaf(w20.z, h0.z, a2); a2 = fmaf(w20.w, h0.w, a2);
            a2 = fmaf(w21.x, h1.x, a2); a2 = fmaf(w21.y, h1.y, a2);
            a2 = fmaf(w21.z, h1.z, a2); a2 = fmaf(w21.w, h1.w, a2);
            a2 = fmaf(w22.x, h2.x, a2); a2 = fmaf(w22.y, h2.y, a2);
            a2 = fmaf(w22.z, h2.z, a2); a2 = fmaf(w22.w, h2.w, a2);
            a2 = fmaf(w23.x, h3.x, a2); a2 = fmaf(w23.y, h3.y, a2);
            a2 = fmaf(w23.z, h3.z, a2); a2 = fmaf(w23.w, h3.w, a2);

            a3 = fmaf(w30.x, h0.x, a3); a3 = fmaf(w30.y, h0.y, a3);
            a3 = fmaf(w30.z, h0.z, a3); a3 = fmaf(w30.w, h0.w, a3);
            a3 = fmaf(w31.x, h1.x, a3); a3 = fmaf(w31.y, h1.y, a3);
            a3 = fmaf(w31.z, h1.z, a3); a3 = fmaf(w31.w, h1.w, a3);
            a3 = fmaf(w32.x, h2.x, a3); a3 = fmaf(w32.y, h2.y, a3);
            a3 = fmaf(w32.z, h2.z, a3); a3 = fmaf(w32.w, h2.w, a3);
            a3 = fmaf(w33.x, h3.x, a3); a3 = fmaf(w33.y, h3.y, a3);
            a3 = fmaf(w33.z, h3.z, a3); a3 = fmaf(w33.w, h3.w, a3);

            #pragma unroll
            for (int m = 1; m < 32; m <<= 1) {
                a0 += __shfl_xor(a0, m);
                a1 += __shfl_xor(a1, m);
                a2 += __shfl_xor(a2, m);
                a3 += __shfl_xor(a3, m);
            }

            if (seg == 0) {
                float ff  = sigm(a0 + gx4.x);
                float iiv = sigm(a1 + gx4.y);
                float ccv = tanh_fast(a2 + gx4.z);
                float ov  = sigm(a3 + gx4.w);
                cold = fmaf(ff, cold, iiv * ccv);
                float hnew = tanh_fast(cold) * ov;
                unsigned long long tv =
                    ((unsigned long long)(unsigned)(t + 1) << 32)
                    | (unsigned long long)__float_as_uint(hnew);
                atomicExch(hdq + (size_t)sc * 512 + b * 8 + r, tv);
                if (t == T_TOTAL - 1) {
                    out[b * 8 + r]       = cold;
                    out[512 + b * 8 + r] = hnew;
                }
            }
        }
        __syncthreads();
    }

    if (wave >= 1 && (tid & 31) == 0) cstate[b * 8 + ((tid - 64) >> 5)] = cold;
}

// ---------------------------------------------------------------------------
extern "C" void kernel_launch(void* const* d_in, const int* in_sizes, int n_in,
                              void* d_out, int out_size, void* d_ws, size_t ws_size,
                              hipStream_t stream)
{
    const float* x  = (const float*)d_in[0];
    const float* wf = (const float*)d_in[1];
    const float* bf = (const float*)d_in[2];
    const float* wi = (const float*)d_in[3];
    const float* bi = (const float*)d_in[4];
    const float* wc = (const float*)d_in[5];
    const float* bc = (const float*)d_in[6];
    const float* wo = (const float*)d_in[7];
    const float* bo = (const float*)d_in[8];
    float* out = (float*)d_out;

    char* wsb = (char*)d_ws;
    unsigned long long* hdq = (unsigned long long*)wsb;      // 2*512*8 = 8192 B
    float* cst = (float*)(wsb + 8192);                       // 512*4   = 2048 B
    const size_t metaBytes = 8192 + 2048;                    // 10240 (16B aligned)
    float* gxbuf = (float*)(wsb + metaBytes);

    size_t gxCapSteps = (ws_size > metaBytes)
                        ? (ws_size - metaBytes) / (2048 * sizeof(float)) : 0;
    int CH = (gxCapSteps < (size_t)T_TOTAL) ? (int)gxCapSteps : T_TOTAL;
    CH &= ~15;
    if (CH < 16) CH = 16;

    hipMemsetAsync(wsb, 0, metaBytes, stream);   // tags=0 (t=0 poll passes), c=0, h=0

    for (int t0 = 0; t0 < T_TOTAL; t0 += CH) {
        int tend  = t0 + CH; if (tend > T_TOTAL) tend = T_TOTAL;
        int steps = tend - t0;
        dim3 ggrid((steps + 15) / 16, 16);
        lstm_gemm_x<<<ggrid, 256, 0, stream>>>(x, wf, wi, wc, wo,
                                               bf, bi, bc, bo, gxbuf, t0, tend);
        lstm_serial<<<NBLK, 320, 0, stream>>>(wf, wi, wc, wo, gxbuf,
                                              hdq, cst, t0, steps, out);
    }
}

// Round 11
// 69599.127 us; speedup vs baseline: 1.8459x; 1.8459x over previous
//
#include <hip/hip_runtime.h>
#include <hip/hip_bf16.h>
#include <cstdint>

// LSTM, T=32768 steps, C=512, I=1024 (x 512 | h 512), fp32.
//   1) gx = Wx@x_t + b  -- GEMM over all timesteps (chunked in ws)
//   2) serial recurrence: 64 blocks x 256 threads (R8 structure, proven 68.6ms,
//      0 bank conflicts). SINGLE CHANGE vs R8: mailbox line-padding.
//      R8 packed 512 tagged words into 32 cache lines -> 16 cross-block
//      atomicExch RMWs serialized per line (~1.6us/step detect cost).
//      Now each block owns a PRIVATE 128B line (8 words + 64B pad): cross-block
//      RMW line-sharing eliminated; readers still do one batched 8-load round.

#define T_TOTAL 32768
#define NBLK 64

__device__ __forceinline__ float sigm(float x) {
    return 1.0f / (1.0f + __expf(-x));
}
__device__ __forceinline__ float tanh_fast(float x) {
    float ax = fabsf(x);
    float e = __expf(2.0f * ax);          // +inf for large ax is fine -> t = 1
    float t = 1.0f - 2.0f / (e + 1.0f);
    return copysignf(t, x);
}

// ---------------------------------------------------------------------------
// GEMM: for fused c-row jg, gate g: block b = jg>>3, r = jg&7:
//   gx word = (jg>>3)*32 + (jg&7)*4 + g   (block-major, float4 per (b,r))
// ---------------------------------------------------------------------------
__global__ __launch_bounds__(256, 1) void lstm_gemm_x(
    const float* __restrict__ x,
    const float* __restrict__ wf, const float* __restrict__ wi,
    const float* __restrict__ wc, const float* __restrict__ wo,
    const float* __restrict__ bf, const float* __restrict__ bi,
    const float* __restrict__ bc, const float* __restrict__ bo,
    float* __restrict__ gx, int t0, int tend)
{
    __shared__ float xs[16][512];
    const int tid = threadIdx.x;
    const int tt0 = t0 + blockIdx.x * 16;
    const int j0  = blockIdx.y * 128;

    #pragma unroll
    for (int i = 0; i < 8; ++i) {
        int idx  = tid + i * 256;
        int trow = idx >> 7, kq = idx & 127;
        int t    = tt0 + trow;
        float4 v = make_float4(0.f, 0.f, 0.f, 0.f);
        if (t < tend) v = *(const float4*)(x + (size_t)t * 512 + kq * 4);
        *(float4*)&xs[trow][kq * 4] = v;
    }
    __syncthreads();

    const int j  = j0 + (tid & 127);
    const int th = tid >> 7;
    const int g  = j >> 9;
    const int jg = j & 511;
    const float* Wg = (g == 0) ? wf : (g == 1) ? wi : (g == 2) ? wc : wo;
    const float* Bg = (g == 0) ? bf : (g == 1) ? bi : (g == 2) ? bc : bo;
    const float* wrow = Wg + (size_t)jg * 1024;

    float acc[8];
    #pragma unroll
    for (int i = 0; i < 8; ++i) acc[i] = 0.f;

    for (int k = 0; k < 512; k += 4) {
        float4 w4 = *(const float4*)(wrow + k);
        #pragma unroll
        for (int tt = 0; tt < 8; ++tt) {
            float4 x4 = *(const float4*)&xs[th * 8 + tt][k];
            acc[tt] = fmaf(w4.x, x4.x, acc[tt]);
            acc[tt] = fmaf(w4.y, x4.y, acc[tt]);
            acc[tt] = fmaf(w4.z, x4.z, acc[tt]);
            acc[tt] = fmaf(w4.w, x4.w, acc[tt]);
        }
    }

    const float bias = Bg[jg];
    const int   obase = (jg >> 3) * 32 + (jg & 7) * 4 + g;
    #pragma unroll
    for (int tt = 0; tt < 8; ++tt) {
        int t = tt0 + th * 8 + tt;
        if (t < tend) gx[(size_t)(t - t0) * 2048 + obase] = acc[tt] + bias;
    }
}

// ---------------------------------------------------------------------------
// Serial recurrence. 64 blocks x 256 threads (1 block/CU, all co-resident).
// Thread map: tid = r*32 + seg; wave w = tid>>6.
// Mailbox layout (THE R11 change): hdq is [2][64 blocks][16 u64] -- each
//   block's 8 tagged words packed in its own 128B line, 64B pad.
//   word (blk,w) holds h[blk*8+w] tagged (t+1)<<32 | bits.
// Reader lane l: word idx l+64i maps to blk=(l>>3)+8i, w=l&7; address =
//   sp*1024 + (l>>3)*16 + (l&7) + 128*i  -- one batched 8-load round.
// Publisher: thread (r, seg==0) atomicExch(hdq + sc*1024 + b*16 + r, tv):
//   only same-block lanes share a line (8 pipelined RMWs, no cross-block
//   serialization).
// Weight LDS layout + compute path: R8 verbatim (0 conflicts).
// Slot-reuse induction identical to R6-R8 (per-word tags).
// ---------------------------------------------------------------------------
__global__ __launch_bounds__(256, 1) void lstm_serial(
    const float* __restrict__ wf, const float* __restrict__ wi,
    const float* __restrict__ wc, const float* __restrict__ wo,
    const float* __restrict__ gx,
    unsigned long long* __restrict__ hdq,   // [2][64][16] tagged h lines
    float* __restrict__ cstate,
    int t0, int steps, float* __restrict__ out)
{
    __shared__ alignas(16) float4 wlds4[4096];  // [w][g][jj][lane] = 64 KB
    __shared__ alignas(16) float  hl[2][512];   // parity-double-buffered h (4 KB)
    const int b   = blockIdx.x;            // 0..63
    const int tid = threadIdx.x;
    const int r   = tid >> 5;              // 0..7
    const int seg = tid & 31;              // 0..31
    const int w   = tid >> 6;              // wave 0..3
    const int l   = tid & 63;              // lane in wave

    // stage weights once: decode flat index -> (w,g,jj,lane)  [R8 verbatim]
    #pragma unroll
    for (int k = 0; k < 16; ++k) {
        int idx = k * 256 + tid;           // 0..4095
        int ll  = idx & 63;
        int jj  = (idx >> 6) & 3;
        int gg  = (idx >> 8) & 3;
        int ww  = idx >> 10;
        const float* Wp = (gg == 0) ? wf : (gg == 1) ? wi : (gg == 2) ? wc : wo;
        int row = b * 8 + ww * 2 + (ll >> 5);
        wlds4[idx] = *(const float4*)(Wp + (size_t)row * 1024 + 512
                                      + 4 * (ll & 31) + 128 * jj);
    }
    float cold = cstate[b * 8 + r];        // only seg==0's copy is used
    __syncthreads();

    const float4* hl4  = (const float4*)hl;
    const int     wbase = w * 1024 + l;    // + g*256 + jj*64

    for (int s = 0; s < steps; ++s) {
        const int t  = t0 + s;
        const int sp = (t & 1) ^ 1;        // slot holding h_{t-1}
        const int sc = t & 1;              // slot receiving h_t

        // gx prefetch (only consumed by seg==0 lanes)
        float4 gx4 = make_float4(0.f, 0.f, 0.f, 0.f);
        if (seg == 0)
            gx4 = *(const float4*)(gx + (size_t)s * 2048 + b * 32 + r * 4);

        // weight regs: 16 lane-linear b128 reads, issue before the poll
        float4 w00 = wlds4[wbase +   0], w01 = wlds4[wbase +  64];
        float4 w02 = wlds4[wbase + 128], w03 = wlds4[wbase + 192];
        float4 w10 = wlds4[wbase + 256], w11 = wlds4[wbase + 320];
        float4 w12 = wlds4[wbase + 384], w13 = wlds4[wbase + 448];
        float4 w20 = wlds4[wbase + 512], w21 = wlds4[wbase + 576];
        float4 w22 = wlds4[wbase + 640], w23 = wlds4[wbase + 704];
        float4 w30 = wlds4[wbase + 768], w31 = wlds4[wbase + 832];
        float4 w32 = wlds4[wbase + 896], w33 = wlds4[wbase + 960];

        if (tid < 64) {                    // wave 0: poll + stage h_{t-1}
            const unsigned need = (unsigned)t;
            // lane l covers word-idx l+64i -> line (l>>3)+8i, word l&7
            const unsigned long long* src =
                hdq + (size_t)sp * 1024 + (tid >> 3) * 16 + (tid & 7);
            unsigned long long v0, v1, v2, v3, v4, v5, v6, v7;
            int guard = 0;
            bool ok = false;
            do {
                v0 = __hip_atomic_load(src,       __ATOMIC_RELAXED, __HIP_MEMORY_SCOPE_AGENT);
                v1 = __hip_atomic_load(src + 128, __ATOMIC_RELAXED, __HIP_MEMORY_SCOPE_AGENT);
                v2 = __hip_atomic_load(src + 256, __ATOMIC_RELAXED, __HIP_MEMORY_SCOPE_AGENT);
                v3 = __hip_atomic_load(src + 384, __ATOMIC_RELAXED, __HIP_MEMORY_SCOPE_AGENT);
                v4 = __hip_atomic_load(src + 512, __ATOMIC_RELAXED, __HIP_MEMORY_SCOPE_AGENT);
                v5 = __hip_atomic_load(src + 640, __ATOMIC_RELAXED, __HIP_MEMORY_SCOPE_AGENT);
                v6 = __hip_atomic_load(src + 768, __ATOMIC_RELAXED, __HIP_MEMORY_SCOPE_AGENT);
                v7 = __hip_atomic_load(src + 896, __ATOMIC_RELAXED, __HIP_MEMORY_SCOPE_AGENT);
                ok = ((unsigned)(v0 >> 32) == need) & ((unsigned)(v1 >> 32) == need)
                   & ((unsigned)(v2 >> 32) == need) & ((unsigned)(v3 >> 32) == need)
                   & ((unsigned)(v4 >> 32) == need) & ((unsigned)(v5 >> 32) == need)
                   & ((unsigned)(v6 >> 32) == need) & ((unsigned)(v7 >> 32) == need);
            } while (!ok && ++guard < (1 << 20));
            hl[sp][tid]       = __uint_as_float((unsigned)v0);
            hl[sp][tid + 64]  = __uint_as_float((unsigned)v1);
            hl[sp][tid + 128] = __uint_as_float((unsigned)v2);
            hl[sp][tid + 192] = __uint_as_float((unsigned)v3);
            hl[sp][tid + 256] = __uint_as_float((unsigned)v4);
            hl[sp][tid + 320] = __uint_as_float((unsigned)v5);
            hl[sp][tid + 384] = __uint_as_float((unsigned)v6);
            hl[sp][tid + 448] = __uint_as_float((unsigned)v7);
        }
        __syncthreads();

        // h: 4 lane-linear b128 reads (r-pairs broadcast)   [R8 verbatim]
        float4 h0 = hl4[sp * 128 + seg];
        float4 h1 = hl4[sp * 128 + seg + 32];
        float4 h2 = hl4[sp * 128 + seg + 64];
        float4 h3 = hl4[sp * 128 + seg + 96];

        float a0 = 0.f, a1 = 0.f, a2 = 0.f, a3 = 0.f;
        a0 = fmaf(w00.x, h0.x, a0); a0 = fmaf(w00.y, h0.y, a0);
        a0 = fmaf(w00.z, h0.z, a0); a0 = fmaf(w00.w, h0.w, a0);
        a0 = fmaf(w01.x, h1.x, a0); a0 = fmaf(w01.y, h1.y, a0);
        a0 = fmaf(w01.z, h1.z, a0); a0 = fmaf(w01.w, h1.w, a0);
        a0 = fmaf(w02.x, h2.x, a0); a0 = fmaf(w02.y, h2.y, a0);
        a0 = fmaf(w02.z, h2.z, a0); a0 = fmaf(w02.w, h2.w, a0);
        a0 = fmaf(w03.x, h3.x, a0); a0 = fmaf(w03.y, h3.y, a0);
        a0 = fmaf(w03.z, h3.z, a0); a0 = fmaf(w03.w, h3.w, a0);

        a1 = fmaf(w10.x, h0.x, a1); a1 = fmaf(w10.y, h0.y, a1);
        a1 = fmaf(w10.z, h0.z, a1); a1 = fmaf(w10.w, h0.w, a1);
        a1 = fmaf(w11.x, h1.x, a1); a1 = fmaf(w11.y, h1.y, a1);
        a1 = fmaf(w11.z, h1.z, a1); a1 = fmaf(w11.w, h1.w, a1);
        a1 = fmaf(w12.x, h2.x, a1); a1 = fmaf(w12.y, h2.y, a1);
        a1 = fmaf(w12.z, h2.z, a1); a1 = fmaf(w12.w, h2.w, a1);
        a1 = fmaf(w13.x, h3.x, a1); a1 = fmaf(w13.y, h3.y, a1);
        a1 = fmaf(w13.z, h3.z, a1); a1 = fmaf(w13.w, h3.w, a1);

        a2 = fmaf(w20.x, h0.x, a2); a2 = fmaf(w20.y, h0.y, a2);
        a2 = fmaf(w20.z, h0.z, a2); a2 = fmaf(w20.w, h0.w, a2);
        a2 = fmaf(w21.x, h1.x, a2); a2 = fmaf(w21.y, h1.y, a2);
        a2 = fmaf(w21.z, h1.z, a2); a2 = fmaf(w21.w, h1.w, a2);
        a2 = fmaf(w22.x, h2.x, a2); a2 = fmaf(w22.y, h2.y, a2);
        a2 = fmaf(w22.z, h2.z, a2); a2 = fmaf(w22.w, h2.w, a2);
        a2 = fmaf(w23.x, h3.x, a2); a2 = fmaf(w23.y, h3.y, a2);
        a2 = fmaf(w23.z, h3.z, a2); a2 = fmaf(w23.w, h3.w, a2);

        a3 = fmaf(w30.x, h0.x, a3); a3 = fmaf(w30.y, h0.y, a3);
        a3 = fmaf(w30.z, h0.z, a3); a3 = fmaf(w30.w, h0.w, a3);
        a3 = fmaf(w31.x, h1.x, a3); a3 = fmaf(w31.y, h1.y, a3);
        a3 = fmaf(w31.z, h1.z, a3); a3 = fmaf(w31.w, h1.w, a3);
        a3 = fmaf(w32.x, h2.x, a3); a3 = fmaf(w32.y, h2.y, a3);
        a3 = fmaf(w32.z, h2.z, a3); a3 = fmaf(w32.w, h2.w, a3);
        a3 = fmaf(w33.x, h3.x, a3); a3 = fmaf(w33.y, h3.y, a3);
        a3 = fmaf(w33.z, h3.z, a3); a3 = fmaf(w33.w, h3.w, a3);

        #pragma unroll
        for (int m = 1; m < 32; m <<= 1) {
            a0 += __shfl_xor(a0, m);
            a1 += __shfl_xor(a1, m);
            a2 += __shfl_xor(a2, m);
            a3 += __shfl_xor(a3, m);
        }

        if (seg == 0) {
            float ff  = sigm(a0 + gx4.x);
            float iiv = sigm(a1 + gx4.y);
            float ccv = tanh_fast(a2 + gx4.z);
            float ov  = sigm(a3 + gx4.w);
            cold = fmaf(ff, cold, iiv * ccv);
            float hnew = tanh_fast(cold) * ov;
            unsigned long long tv = ((unsigned long long)(unsigned)(t + 1) << 32)
                                  | (unsigned long long)__float_as_uint(hnew);
            // private line per block: no cross-block RMW serialization
            atomicExch(hdq + (size_t)sc * 1024 + b * 16 + r, tv);
            if (t == T_TOTAL - 1) {
                out[b * 8 + r]       = cold;
                out[512 + b * 8 + r] = hnew;
            }
        }
    }

    if (seg == 0) cstate[b * 8 + r] = cold;
}

// ---------------------------------------------------------------------------
extern "C" void kernel_launch(void* const* d_in, const int* in_sizes, int n_in,
                              void* d_out, int out_size, void* d_ws, size_t ws_size,
                              hipStream_t stream)
{
    const float* x  = (const float*)d_in[0];
    const float* wf = (const float*)d_in[1];
    const float* bf = (const float*)d_in[2];
    const float* wi = (const float*)d_in[3];
    const float* bi = (const float*)d_in[4];
    const float* wc = (const float*)d_in[5];
    const float* bc = (const float*)d_in[6];
    const float* wo = (const float*)d_in[7];
    const float* bo = (const float*)d_in[8];
    float* out = (float*)d_out;

    char* wsb = (char*)d_ws;
    unsigned long long* hdq = (unsigned long long*)wsb;      // 2*64*16*8 = 16384 B
    float* cst = (float*)(wsb + 16384);                      // 512*4     = 2048 B
    const size_t metaBytes = 16384 + 2048;                   // 18432 (16B aligned)
    float* gxbuf = (float*)(wsb + metaBytes);

    size_t gxCapSteps = (ws_size > metaBytes)
                        ? (ws_size - metaBytes) / (2048 * sizeof(float)) : 0;
    int CH = (gxCapSteps < (size_t)T_TOTAL) ? (int)gxCapSteps : T_TOTAL;
    CH &= ~15;
    if (CH < 16) CH = 16;

    hipMemsetAsync(wsb, 0, metaBytes, stream);   // tags=0 (t=0 poll passes), c=0, h=0

    for (int t0 = 0; t0 < T_TOTAL; t0 += CH) {
        int tend  = t0 + CH; if (tend > T_TOTAL) tend = T_TOTAL;
        int steps = tend - t0;
        dim3 ggrid((steps + 15) / 16, 16);
        lstm_gemm_x<<<ggrid, 256, 0, stream>>>(x, wf, wi, wc, wo,
                                               bf, bi, bc, bo, gxbuf, t0, tend);
        lstm_serial<<<NBLK, 256, 0, stream>>>(wf, wi, wc, wo, gxbuf,
                                              hdq, cst, t0, steps, out);
    }
}

// Round 12
// 68410.266 us; speedup vs baseline: 1.8780x; 1.0174x over previous
//
#include <hip/hip_runtime.h>
#include <hip/hip_bf16.h>
#include <cstdint>

// LSTM, T=32768 steps, C=512, I=1024 (x 512 | h 512), fp32.
//   1) gx = Wx@x_t + b  -- GEMM over all timesteps (chunked in ws)
//   2) serial recurrence: 64 blocks x 256 threads (R8/R11 structure, proven,
//      0 bank conflicts). SINGLE CHANGE vs R11: publish via relaxed agent-scope
//      atomic STORE (fire-and-forget, no RMW ownership round trip) instead of
//      atomicExch. R11 proved line geometry neutral; this isolates op class.

#define T_TOTAL 32768
#define NBLK 64

__device__ __forceinline__ float sigm(float x) {
    return 1.0f / (1.0f + __expf(-x));
}
__device__ __forceinline__ float tanh_fast(float x) {
    float ax = fabsf(x);
    float e = __expf(2.0f * ax);          // +inf for large ax is fine -> t = 1
    float t = 1.0f - 2.0f / (e + 1.0f);
    return copysignf(t, x);
}

// ---------------------------------------------------------------------------
// GEMM: for fused c-row jg, gate g: block b = jg>>3, r = jg&7:
//   gx word = (jg>>3)*32 + (jg&7)*4 + g   (block-major, float4 per (b,r))
// ---------------------------------------------------------------------------
__global__ __launch_bounds__(256, 1) void lstm_gemm_x(
    const float* __restrict__ x,
    const float* __restrict__ wf, const float* __restrict__ wi,
    const float* __restrict__ wc, const float* __restrict__ wo,
    const float* __restrict__ bf, const float* __restrict__ bi,
    const float* __restrict__ bc, const float* __restrict__ bo,
    float* __restrict__ gx, int t0, int tend)
{
    __shared__ float xs[16][512];
    const int tid = threadIdx.x;
    const int tt0 = t0 + blockIdx.x * 16;
    const int j0  = blockIdx.y * 128;

    #pragma unroll
    for (int i = 0; i < 8; ++i) {
        int idx  = tid + i * 256;
        int trow = idx >> 7, kq = idx & 127;
        int t    = tt0 + trow;
        float4 v = make_float4(0.f, 0.f, 0.f, 0.f);
        if (t < tend) v = *(const float4*)(x + (size_t)t * 512 + kq * 4);
        *(float4*)&xs[trow][kq * 4] = v;
    }
    __syncthreads();

    const int j  = j0 + (tid & 127);
    const int th = tid >> 7;
    const int g  = j >> 9;
    const int jg = j & 511;
    const float* Wg = (g == 0) ? wf : (g == 1) ? wi : (g == 2) ? wc : wo;
    const float* Bg = (g == 0) ? bf : (g == 1) ? bi : (g == 2) ? bc : bo;
    const float* wrow = Wg + (size_t)jg * 1024;

    float acc[8];
    #pragma unroll
    for (int i = 0; i < 8; ++i) acc[i] = 0.f;

    for (int k = 0; k < 512; k += 4) {
        float4 w4 = *(const float4*)(wrow + k);
        #pragma unroll
        for (int tt = 0; tt < 8; ++tt) {
            float4 x4 = *(const float4*)&xs[th * 8 + tt][k];
            acc[tt] = fmaf(w4.x, x4.x, acc[tt]);
            acc[tt] = fmaf(w4.y, x4.y, acc[tt]);
            acc[tt] = fmaf(w4.z, x4.z, acc[tt]);
            acc[tt] = fmaf(w4.w, x4.w, acc[tt]);
        }
    }

    const float bias = Bg[jg];
    const int   obase = (jg >> 3) * 32 + (jg & 7) * 4 + g;
    #pragma unroll
    for (int tt = 0; tt < 8; ++tt) {
        int t = tt0 + th * 8 + tt;
        if (t < tend) gx[(size_t)(t - t0) * 2048 + obase] = acc[tt] + bias;
    }
}

// ---------------------------------------------------------------------------
// Serial recurrence. 64 blocks x 256 threads (1 block/CU, all co-resident).
// Thread map: tid = r*32 + seg; wave w = tid>>6.
// Mailbox: hdq[2][64 blocks][16 u64] -- block-private 128B line (R11 layout).
//   word (blk,w) holds h[blk*8+w] tagged (t+1)<<32 | bits.
// Publisher (R12 change): seg==0 thread does ONE relaxed agent atomic STORE of
//   its tagged word -- no RMW ownership round trip; same-line stores merge.
// Reader lane l: word idx l+64i -> line (l>>3)+8i, word l&7; one batched
//   8-load round per poll iteration.
// Weight LDS layout + compute path: R8 verbatim (0 conflicts).
// Slot-reuse induction identical to R6-R11 (per-word tags).
// ---------------------------------------------------------------------------
__global__ __launch_bounds__(256, 1) void lstm_serial(
    const float* __restrict__ wf, const float* __restrict__ wi,
    const float* __restrict__ wc, const float* __restrict__ wo,
    const float* __restrict__ gx,
    unsigned long long* __restrict__ hdq,   // [2][64][16] tagged h lines
    float* __restrict__ cstate,
    int t0, int steps, float* __restrict__ out)
{
    __shared__ alignas(16) float4 wlds4[4096];  // [w][g][jj][lane] = 64 KB
    __shared__ alignas(16) float  hl[2][512];   // parity-double-buffered h (4 KB)
    const int b   = blockIdx.x;            // 0..63
    const int tid = threadIdx.x;
    const int r   = tid >> 5;              // 0..7
    const int seg = tid & 31;              // 0..31
    const int w   = tid >> 6;              // wave 0..3
    const int l   = tid & 63;              // lane in wave

    // stage weights once: decode flat index -> (w,g,jj,lane)  [R8 verbatim]
    #pragma unroll
    for (int k = 0; k < 16; ++k) {
        int idx = k * 256 + tid;           // 0..4095
        int ll  = idx & 63;
        int jj  = (idx >> 6) & 3;
        int gg  = (idx >> 8) & 3;
        int ww  = idx >> 10;
        const float* Wp = (gg == 0) ? wf : (gg == 1) ? wi : (gg == 2) ? wc : wo;
        int row = b * 8 + ww * 2 + (ll >> 5);
        wlds4[idx] = *(const float4*)(Wp + (size_t)row * 1024 + 512
                                      + 4 * (ll & 31) + 128 * jj);
    }
    float cold = cstate[b * 8 + r];        // only seg==0's copy is used
    __syncthreads();

    const float4* hl4  = (const float4*)hl;
    const int     wbase = w * 1024 + l;    // + g*256 + jj*64

    for (int s = 0; s < steps; ++s) {
        const int t  = t0 + s;
        const int sp = (t & 1) ^ 1;        // slot holding h_{t-1}
        const int sc = t & 1;              // slot receiving h_t

        // gx prefetch (only consumed by seg==0 lanes)
        float4 gx4 = make_float4(0.f, 0.f, 0.f, 0.f);
        if (seg == 0)
            gx4 = *(const float4*)(gx + (size_t)s * 2048 + b * 32 + r * 4);

        // weight regs: 16 lane-linear b128 reads, issue before the poll
        float4 w00 = wlds4[wbase +   0], w01 = wlds4[wbase +  64];
        float4 w02 = wlds4[wbase + 128], w03 = wlds4[wbase + 192];
        float4 w10 = wlds4[wbase + 256], w11 = wlds4[wbase + 320];
        float4 w12 = wlds4[wbase + 384], w13 = wlds4[wbase + 448];
        float4 w20 = wlds4[wbase + 512], w21 = wlds4[wbase + 576];
        float4 w22 = wlds4[wbase + 640], w23 = wlds4[wbase + 704];
        float4 w30 = wlds4[wbase + 768], w31 = wlds4[wbase + 832];
        float4 w32 = wlds4[wbase + 896], w33 = wlds4[wbase + 960];

        if (tid < 64) {                    // wave 0: poll + stage h_{t-1}
            const unsigned need = (unsigned)t;
            // lane l covers word-idx l+64i -> line (l>>3)+8i, word l&7
            const unsigned long long* src =
                hdq + (size_t)sp * 1024 + (tid >> 3) * 16 + (tid & 7);
            unsigned long long v0, v1, v2, v3, v4, v5, v6, v7;
            int guard = 0;
            bool ok = false;
            do {
                v0 = __hip_atomic_load(src,       __ATOMIC_RELAXED, __HIP_MEMORY_SCOPE_AGENT);
                v1 = __hip_atomic_load(src + 128, __ATOMIC_RELAXED, __HIP_MEMORY_SCOPE_AGENT);
                v2 = __hip_atomic_load(src + 256, __ATOMIC_RELAXED, __HIP_MEMORY_SCOPE_AGENT);
                v3 = __hip_atomic_load(src + 384, __ATOMIC_RELAXED, __HIP_MEMORY_SCOPE_AGENT);
                v4 = __hip_atomic_load(src + 512, __ATOMIC_RELAXED, __HIP_MEMORY_SCOPE_AGENT);
                v5 = __hip_atomic_load(src + 640, __ATOMIC_RELAXED, __HIP_MEMORY_SCOPE_AGENT);
                v6 = __hip_atomic_load(src + 768, __ATOMIC_RELAXED, __HIP_MEMORY_SCOPE_AGENT);
                v7 = __hip_atomic_load(src + 896, __ATOMIC_RELAXED, __HIP_MEMORY_SCOPE_AGENT);
                ok = ((unsigned)(v0 >> 32) == need) & ((unsigned)(v1 >> 32) == need)
                   & ((unsigned)(v2 >> 32) == need) & ((unsigned)(v3 >> 32) == need)
                   & ((unsigned)(v4 >> 32) == need) & ((unsigned)(v5 >> 32) == need)
                   & ((unsigned)(v6 >> 32) == need) & ((unsigned)(v7 >> 32) == need);
            } while (!ok && ++guard < (1 << 20));
            hl[sp][tid]       = __uint_as_float((unsigned)v0);
            hl[sp][tid + 64]  = __uint_as_float((unsigned)v1);
            hl[sp][tid + 128] = __uint_as_float((unsigned)v2);
            hl[sp][tid + 192] = __uint_as_float((unsigned)v3);
            hl[sp][tid + 256] = __uint_as_float((unsigned)v4);
            hl[sp][tid + 320] = __uint_as_float((unsigned)v5);
            hl[sp][tid + 384] = __uint_as_float((unsigned)v6);
            hl[sp][tid + 448] = __uint_as_float((unsigned)v7);
        }
        __syncthreads();

        // h: 4 lane-linear b128 reads (r-pairs broadcast)   [R8 verbatim]
        float4 h0 = hl4[sp * 128 + seg];
        float4 h1 = hl4[sp * 128 + seg + 32];
        float4 h2 = hl4[sp * 128 + seg + 64];
        float4 h3 = hl4[sp * 128 + seg + 96];

        float a0 = 0.f, a1 = 0.f, a2 = 0.f, a3 = 0.f;
        a0 = fmaf(w00.x, h0.x, a0); a0 = fmaf(w00.y, h0.y, a0);
        a0 = fmaf(w00.z, h0.z, a0); a0 = fmaf(w00.w, h0.w, a0);
        a0 = fmaf(w01.x, h1.x, a0); a0 = fmaf(w01.y, h1.y, a0);
        a0 = fmaf(w01.z, h1.z, a0); a0 = fmaf(w01.w, h1.w, a0);
        a0 = fmaf(w02.x, h2.x, a0); a0 = fmaf(w02.y, h2.y, a0);
        a0 = fmaf(w02.z, h2.z, a0); a0 = fmaf(w02.w, h2.w, a0);
        a0 = fmaf(w03.x, h3.x, a0); a0 = fmaf(w03.y, h3.y, a0);
        a0 = fmaf(w03.z, h3.z, a0); a0 = fmaf(w03.w, h3.w, a0);

        a1 = fmaf(w10.x, h0.x, a1); a1 = fmaf(w10.y, h0.y, a1);
        a1 = fmaf(w10.z, h0.z, a1); a1 = fmaf(w10.w, h0.w, a1);
        a1 = fmaf(w11.x, h1.x, a1); a1 = fmaf(w11.y, h1.y, a1);
        a1 = fmaf(w11.z, h1.z, a1); a1 = fmaf(w11.w, h1.w, a1);
        a1 = fmaf(w12.x, h2.x, a1); a1 = fmaf(w12.y, h2.y, a1);
        a1 = fmaf(w12.z, h2.z, a1); a1 = fmaf(w12.w, h2.w, a1);
        a1 = fmaf(w13.x, h3.x, a1); a1 = fmaf(w13.y, h3.y, a1);
        a1 = fmaf(w13.z, h3.z, a1); a1 = fmaf(w13.w, h3.w, a1);

        a2 = fmaf(w20.x, h0.x, a2); a2 = fmaf(w20.y, h0.y, a2);
        a2 = fmaf(w20.z, h0.z, a2); a2 = fmaf(w20.w, h0.w, a2);
        a2 = fmaf(w21.x, h1.x, a2); a2 = fmaf(w21.y, h1.y, a2);
        a2 = fmaf(w21.z, h1.z, a2); a2 = fmaf(w21.w, h1.w, a2);
        a2 = fmaf(w22.x, h2.x, a2); a2 = fmaf(w22.y, h2.y, a2);
        a2 = fmaf(w22.z, h2.z, a2); a2 = fmaf(w22.w, h2.w, a2);
        a2 = fmaf(w23.x, h3.x, a2); a2 = fmaf(w23.y, h3.y, a2);
        a2 = fmaf(w23.z, h3.z, a2); a2 = fmaf(w23.w, h3.w, a2);

        a3 = fmaf(w30.x, h0.x, a3); a3 = fmaf(w30.y, h0.y, a3);
        a3 = fmaf(w30.z, h0.z, a3); a3 = fmaf(w30.w, h0.w, a3);
        a3 = fmaf(w31.x, h1.x, a3); a3 = fmaf(w31.y, h1.y, a3);
        a3 = fmaf(w31.z, h1.z, a3); a3 = fmaf(w31.w, h1.w, a3);
        a3 = fmaf(w32.x, h2.x, a3); a3 = fmaf(w32.y, h2.y, a3);
        a3 = fmaf(w32.z, h2.z, a3); a3 = fmaf(w32.w, h2.w, a3);
        a3 = fmaf(w33.x, h3.x, a3); a3 = fmaf(w33.y, h3.y, a3);
        a3 = fmaf(w33.z, h3.z, a3); a3 = fmaf(w33.w, h3.w, a3);

        #pragma unroll
        for (int m = 1; m < 32; m <<= 1) {
            a0 += __shfl_xor(a0, m);
            a1 += __shfl_xor(a1, m);
            a2 += __shfl_xor(a2, m);
            a3 += __shfl_xor(a3, m);
        }

        if (seg == 0) {
            float ff  = sigm(a0 + gx4.x);
            float iiv = sigm(a1 + gx4.y);
            float ccv = tanh_fast(a2 + gx4.z);
            float ov  = sigm(a3 + gx4.w);
            cold = fmaf(ff, cold, iiv * ccv);
            float hnew = tanh_fast(cold) * ov;
            unsigned long long tv = ((unsigned long long)(unsigned)(t + 1) << 32)
                                  | (unsigned long long)__float_as_uint(hnew);
            // R12: fire-and-forget agent-scope atomic STORE (no RMW ownership)
            __hip_atomic_store(hdq + (size_t)sc * 1024 + b * 16 + r, tv,
                               __ATOMIC_RELAXED, __HIP_MEMORY_SCOPE_AGENT);
            if (t == T_TOTAL - 1) {
                out[b * 8 + r]       = cold;
                out[512 + b * 8 + r] = hnew;
            }
        }
    }

    if (seg == 0) cstate[b * 8 + r] = cold;
}

// ---------------------------------------------------------------------------
extern "C" void kernel_launch(void* const* d_in, const int* in_sizes, int n_in,
                              void* d_out, int out_size, void* d_ws, size_t ws_size,
                              hipStream_t stream)
{
    const float* x  = (const float*)d_in[0];
    const float* wf = (const float*)d_in[1];
    const float* bf = (const float*)d_in[2];
    const float* wi = (const float*)d_in[3];
    const float* bi = (const float*)d_in[4];
    const float* wc = (const float*)d_in[5];
    const float* bc = (const float*)d_in[6];
    const float* wo = (const float*)d_in[7];
    const float* bo = (const float*)d_in[8];
    float* out = (float*)d_out;

    char* wsb = (char*)d_ws;
    unsigned long long* hdq = (unsigned long long*)wsb;      // 2*64*16*8 = 16384 B
    float* cst = (float*)(wsb + 16384);                      // 512*4     = 2048 B
    const size_t metaBytes = 16384 + 2048;                   // 18432 (16B aligned)
    float* gxbuf = (float*)(wsb + metaBytes);

    size_t gxCapSteps = (ws_size > metaBytes)
                        ? (ws_size - metaBytes) / (2048 * sizeof(float)) : 0;
    int CH = (gxCapSteps < (size_t)T_TOTAL) ? (int)gxCapSteps : T_TOTAL;
    CH &= ~15;
    if (CH < 16) CH = 16;

    hipMemsetAsync(wsb, 0, metaBytes, stream);   // tags=0 (t=0 poll passes), c=0, h=0

    for (int t0 = 0; t0 < T_TOTAL; t0 += CH) {
        int tend  = t0 + CH; if (tend > T_TOTAL) tend = T_TOTAL;
        int steps = tend - t0;
        dim3 ggrid((steps + 15) / 16, 16);
        lstm_gemm_x<<<ggrid, 256, 0, stream>>>(x, wf, wi, wc, wo,
                                               bf, bi, bc, bo, gxbuf, t0, tend);
        lstm_serial<<<NBLK, 256, 0, stream>>>(wf, wi, wc, wo, gxbuf,
                                              hdq, cst, t0, steps, out);
    }
}